// Round 8
// baseline (134.456 us; speedup 1.0000x reference)
//
#include <hip/hip_runtime.h>

// NCC loss, fused z-sweep, v8 = R7 (256-thr, 16x16 tile, macro-literal ring)
// + single barrier per slice via parity double-buffered st/xf (R4 scheme)
// + z-invariant stage geometry hoisted.
// Per slice: [stage(s+1)->st[p^1] || xf(s): st[p]->xf[p]] SYNC [yf(s): xf[p]]
// Grid 1600 x 256, LDS ~24.6 KB.

#define TX 16
#define TY 16
#define ZC 20
#define PH 24          // TY+8
#define PW 24          // TX+8
#define XFP 16         // float4 row stride
#define NSTEP 28       // ZC+8
#define NN 160
#define NPLANE (160*160)

__global__ void ncc_zero_ws(float* ws) { ws[0] = 0.0f; }

__global__ __launch_bounds__(256)
void ncc_fused(const float* __restrict__ pred, const float* __restrict__ target,
               float* __restrict__ ws) {
  __shared__ float2 st[2][PH * PW];      // staged (t,p)        9.2 KB
  __shared__ float4 xf4[2][PH * XFP];    // x-filt 4 moments   12.3 KB
  __shared__ float  xf1[2][PH * XFP];    // x-filt tp           3.1 KB
  __shared__ float  wsum[4];

  const int tid = threadIdx.x;
  const int tx = tid & 15;
  const int ty = tid >> 4;               // 0..15

  int b = blockIdx.x;
  const int xt = b % 10; b /= 10;
  const int yt = b % 10; b /= 10;
  const int zc = b % 8;  b /= 8;
  const int x0 = xt * TX, y0 = yt * TY, z0 = zc * ZC;
  const size_t bbase = (size_t)b * (size_t)NN * (size_t)NPLANE;

  // ---- z-invariant stage geometry: 3 strided positions/thread ----
  // pos = tid, tid+256, tid+512 (<576)
  int   soff[3];  bool svalid[3];
  #pragma unroll
  for (int i = 0; i < 3; ++i) {
    const int pos = tid + 256 * i;
    const int yy = pos / PW, xx = pos - yy * PW;
    const int gy = y0 + yy - 4, gx = x0 + xx - 4;
    svalid[i] = (pos < PH * PW) && ((unsigned)gy < NN) && ((unsigned)gx < NN);
    soff[i] = gy * NN + gx;
  }

  float buf0[9], buf1[9], buf2[9], buf3[9], buf4[9];
  float run0 = 0, run1 = 0, run2 = 0, run3 = 0, run4 = 0;
  #pragma unroll
  for (int j = 0; j < 9; ++j) { buf0[j]=0; buf1[j]=0; buf2[j]=0; buf3[j]=0; buf4[j]=0; }
  float acc = 0.0f;
  const float inv_kvol = 1.0f / 729.0f;

  // ---- stage slice SS into parity buffer (skip if z-invalid) ----
#define STAGE(SS) do {                                                        \
    const int zi_ = z0 - 4 + (SS);                                            \
    if ((unsigned)zi_ < NN) {                                                 \
      float2* dst_ = st[(SS) & 1];                                            \
      const size_t zb_ = bbase + (size_t)zi_ * (size_t)NPLANE;                \
      _Pragma("unroll")                                                       \
      for (int i_ = 0; i_ < 3; ++i_) {                                        \
        const int pos_ = tid + 256 * i_;                                      \
        if (pos_ < PH * PW) {                                                 \
          float tv_ = 0.0f, pv_ = 0.0f;                                       \
          if (svalid[i_]) {                                                   \
            tv_ = target[zb_ + soff[i_]];                                     \
            pv_ = pred[zb_ + soff[i_]];                                       \
          }                                                                   \
          dst_[pos_] = make_float2(tv_, pv_);                                 \
        }                                                                     \
      }                                                                       \
    }                                                                         \
  } while (0)

  // ---- slice body: PP = literal ring slot = s % 9; DO_STAGE stages s+1 ----
#define ZBODY(PP, S_EXPR, DO_STAGE) do {                                      \
    const int s = (S_EXPR);                                                   \
    const int zi = z0 - 4 + s;                                                \
    const bool zvalid = ((unsigned)zi < NN);     /* block-uniform */          \
    const int par = s & 1;                                                    \
    if (DO_STAGE) { STAGE(s + 1); }                                           \
    if (zvalid) {                                                             \
      const float2* stA = st[par];                                            \
      float4* xa_ = xf4[par];                                                 \
      float*  xb_ = xf1[par];                                                 \
      for (int pos = tid; pos < PH * TX; pos += 256) {                        \
        const int yy = pos >> 4;                                              \
        const int xx = pos & 15;                                              \
        float s_t = 0, s_p = 0, s_t2 = 0, s_p2 = 0, s_tp = 0;                 \
        _Pragma("unroll")                                                     \
        for (int dx = 0; dx < 9; ++dx) {                                      \
          const float2 v = stA[yy * PW + xx + dx];                            \
          s_t += v.x;                                                         \
          s_p += v.y;                                                         \
          s_t2 = fmaf(v.x, v.x, s_t2);                                        \
          s_p2 = fmaf(v.y, v.y, s_p2);                                        \
          s_tp = fmaf(v.x, v.y, s_tp);                                        \
        }                                                                     \
        xa_[yy * XFP + xx] = make_float4(s_t, s_p, s_t2, s_p2);               \
        xb_[yy * XFP + xx] = s_tp;                                            \
      }                                                                       \
    }                                                                         \
    __syncthreads();   /* the ONE barrier: xf[par]/st[par^1] visible */       \
    float cur0 = 0, cur1 = 0, cur2 = 0, cur3 = 0, cur4 = 0;                   \
    if (zvalid) {                                                             \
      const float4* xa_ = xf4[par];                                           \
      const float*  xb_ = xf1[par];                                           \
      _Pragma("unroll")                                                       \
      for (int dy = 0; dy < 9; ++dy) {                                        \
        const float4 a = xa_[(ty + dy) * XFP + tx];                           \
        const float  c = xb_[(ty + dy) * XFP + tx];                           \
        cur0 += a.x; cur1 += a.y; cur2 += a.z; cur3 += a.w; cur4 += c;        \
      }                                                                       \
    }                                                                         \
    run0 += cur0 - buf0[(PP)]; buf0[(PP)] = cur0;                             \
    run1 += cur1 - buf1[(PP)]; buf1[(PP)] = cur1;                             \
    run2 += cur2 - buf2[(PP)]; buf2[(PP)] = cur2;                             \
    run3 += cur3 - buf3[(PP)]; buf3[(PP)] = cur3;                             \
    run4 += cur4 - buf4[(PP)]; buf4[(PP)] = cur4;                             \
    if (s >= 8) {                                                             \
      const float tavg = run0 * inv_kvol;                                     \
      const float pavg = run1 * inv_kvol;                                     \
      const float cross = run4 - pavg * run0;                                 \
      const float tvar  = run2 - tavg * run0;                                 \
      const float pvar  = run3 - pavg * run1;                                 \
      acc += (cross * cross) / (tvar * pvar + 1e-5f);                         \
    }                                                                         \
  } while (0)

  // ---- prologue: stage slice 0 ----
  STAGE(0);
  __syncthreads();

  // slices 0..26 (always stage s+1 <= 27); tail slice 27 (slot 0, no stage)
  for (int s0 = 0; s0 < 27; s0 += 9) {
    ZBODY(0, s0 + 0, 1); ZBODY(1, s0 + 1, 1); ZBODY(2, s0 + 2, 1);
    ZBODY(3, s0 + 3, 1); ZBODY(4, s0 + 4, 1); ZBODY(5, s0 + 5, 1);
    ZBODY(6, s0 + 6, 1); ZBODY(7, s0 + 7, 1); ZBODY(8, s0 + 8, 1);
  }
  ZBODY(0, 27, 0);
#undef ZBODY
#undef STAGE

  // ---- reduction: wave shuffle -> LDS -> one atomicAdd per block ----
  #pragma unroll
  for (int off = 32; off > 0; off >>= 1)
    acc += __shfl_down(acc, off, 64);
  if ((tid & 63) == 0) wsum[tid >> 6] = acc;
  __syncthreads();
  if (tid == 0) {
    float tot = wsum[0] + wsum[1] + wsum[2] + wsum[3];
    atomicAdd(ws, tot);
  }
}

__global__ void ncc_finalize(const float* __restrict__ ws, float* __restrict__ out) {
  out[0] = -ws[0] * (1.0f / 8192000.0f);
}

extern "C" void kernel_launch(void* const* d_in, const int* in_sizes, int n_in,
                              void* d_out, int out_size, void* d_ws, size_t ws_size,
                              hipStream_t stream) {
  const float* pred   = (const float*)d_in[0];
  const float* target = (const float*)d_in[1];
  float* out = (float*)d_out;
  float* ws  = (float*)d_ws;

  ncc_zero_ws<<<1, 1, 0, stream>>>(ws);
  // grid: 10 x-tiles * 10 y-tiles * 8 z-chunks * 2 batches = 1600 blocks
  ncc_fused<<<1600, 256, 0, stream>>>(pred, target, ws);
  ncc_finalize<<<1, 1, 0, stream>>>(ws, out);
}

// Round 9
// 90.630 us; speedup vs baseline: 1.4836x; 1.4836x over previous
//
#include <hip/hip_runtime.h>

// NCC loss, fused z-sweep, v9 = R7 EXACT two-barrier structure + T14 split:
// loads for slice s+1 issued after barrier B (hidden under yf+ring+NCC),
// consumed by st ds_write at top of body s+1. Offsets hoisted (z-invariant),
// prefetch in 6 named regs (static). Grid 1600 x 256, LDS ~12.6 KB.

#define TX 16
#define TY 16
#define ZC 20
#define PH 24          // TY+8
#define PW 24          // TX+8
#define XFP 16         // float4 row stride
#define NSTEP 28       // ZC+8
#define NN 160
#define NPLANE (160*160)

__global__ void ncc_zero_ws(float* ws) { ws[0] = 0.0f; }

__global__ __launch_bounds__(256)
void ncc_fused(const float* __restrict__ pred, const float* __restrict__ target,
               float* __restrict__ ws) {
  __shared__ float2 st[PH * PW];       // staged (t,p)          4.6 KB
  __shared__ float4 xf4[PH * XFP];     // x-filt (t,p,t2,p2)    6.1 KB
  __shared__ float  xf1[PH * XFP];     // x-filt tp             1.5 KB
  __shared__ float  wsum[4];

  const int tid = threadIdx.x;
  const int tx = tid & 15;
  const int ty = tid >> 4;             // 0..15

  int b = blockIdx.x;
  const int xt = b % 10; b /= 10;
  const int yt = b % 10; b /= 10;
  const int zc = b % 8;  b /= 8;
  const int x0 = xt * TX, y0 = yt * TY, z0 = zc * ZC;
  const size_t bbase = (size_t)b * (size_t)NN * (size_t)NPLANE;

  // ---- hoisted z-invariant stage geometry (3 strided positions) ----
  int soff0, soff1, soff2;
  bool sv0, sv1, sv2;
  {
    const int yy = tid / PW, xx = tid - yy * PW;
    const int gy = y0 + yy - 4, gx = x0 + xx - 4;
    sv0 = ((unsigned)gy < NN) && ((unsigned)gx < NN);
    soff0 = gy * NN + gx;
  }
  {
    const int pos = tid + 256;
    const int yy = pos / PW, xx = pos - yy * PW;
    const int gy = y0 + yy - 4, gx = x0 + xx - 4;
    sv1 = ((unsigned)gy < NN) && ((unsigned)gx < NN);
    soff1 = gy * NN + gx;
  }
  {
    const int pos = tid + 512;
    const int yy = pos / PW, xx = pos - yy * PW;
    const int gy = y0 + yy - 4, gx = x0 + xx - 4;
    sv2 = (tid < 64) && ((unsigned)gy < NN) && ((unsigned)gx < NN);
    soff2 = gy * NN + gx;
  }

  float rt0, rp0, rt1, rp1, rt2, rp2;  // prefetch regs (named -> static)

  // issue loads for slice SS (z-guarded; per-lane exec-masked by sv*)
#define PRELOAD(SS) do {                                                      \
    const int zi_ = z0 - 4 + (SS);                                            \
    if ((unsigned)zi_ < NN) {                                                 \
      const size_t zb_ = bbase + (size_t)zi_ * (size_t)NPLANE;                \
      rt0 = sv0 ? target[zb_ + soff0] : 0.0f;                                 \
      rp0 = sv0 ? pred[zb_ + soff0]   : 0.0f;                                 \
      rt1 = sv1 ? target[zb_ + soff1] : 0.0f;                                 \
      rp1 = sv1 ? pred[zb_ + soff1]   : 0.0f;                                 \
      rt2 = sv2 ? target[zb_ + soff2] : 0.0f;                                 \
      rp2 = sv2 ? pred[zb_ + soff2]   : 0.0f;                                 \
    }                                                                         \
  } while (0)

  float buf0[9], buf1[9], buf2[9], buf3[9], buf4[9];
  float run0 = 0, run1 = 0, run2 = 0, run3 = 0, run4 = 0;
  #pragma unroll
  for (int j = 0; j < 9; ++j) { buf0[j]=0; buf1[j]=0; buf2[j]=0; buf3[j]=0; buf4[j]=0; }
  float acc = 0.0f;
  const float inv_kvol = 1.0f / 729.0f;

  // ---- slice body; PP literal -> static ring indexing (rule #20) ----
#define ZBODY(PP) do {                                                        \
    const int s = s0 + (PP);                                                  \
    if (s < NSTEP) {                                                          \
      const int zi = z0 - 4 + s;                                              \
      const bool zvalid = ((unsigned)zi < NN);    /* block-uniform */         \
      float cur0 = 0, cur1 = 0, cur2 = 0, cur3 = 0, cur4 = 0;                 \
      if (zvalid) {                                                           \
        /* write st from prefetch regs (loaded last body; waitcnt here) */    \
        st[tid]       = make_float2(rt0, rp0);                                \
        st[tid + 256] = make_float2(rt1, rp1);                                \
        if (tid < 64) st[tid + 512] = make_float2(rt2, rp2);                  \
        __syncthreads();   /* A: st visible */                                \
        for (int pos = tid; pos < PH * TX; pos += 256) {                      \
          const int yy = pos >> 4;                                            \
          const int xx = pos & 15;                                            \
          float s_t = 0, s_p = 0, s_t2 = 0, s_p2 = 0, s_tp = 0;               \
          _Pragma("unroll")                                                   \
          for (int dx = 0; dx < 9; ++dx) {                                    \
            const float2 v = st[yy * PW + xx + dx];                           \
            s_t += v.x;                                                       \
            s_p += v.y;                                                       \
            s_t2 = fmaf(v.x, v.x, s_t2);                                      \
            s_p2 = fmaf(v.y, v.y, s_p2);                                      \
            s_tp = fmaf(v.x, v.y, s_tp);                                      \
          }                                                                   \
          xf4[yy * XFP + xx] = make_float4(s_t, s_p, s_t2, s_p2);             \
          xf1[yy * XFP + xx] = s_tp;                                          \
        }                                                                     \
        __syncthreads();   /* B: xf visible; st reads done */                 \
      }                                                                       \
      /* T14: issue next slice's loads; complete during yf+ring+NCC */        \
      if (s + 1 < NSTEP) { PRELOAD(s + 1); }                                  \
      if (zvalid) {                                                           \
        _Pragma("unroll")                                                     \
        for (int dy = 0; dy < 9; ++dy) {                                      \
          const float4 a = xf4[(ty + dy) * XFP + tx];                         \
          const float  c = xf1[(ty + dy) * XFP + tx];                         \
          cur0 += a.x; cur1 += a.y; cur2 += a.z; cur3 += a.w; cur4 += c;      \
        }                                                                     \
      }                                                                       \
      run0 += cur0 - buf0[(PP)]; buf0[(PP)] = cur0;                           \
      run1 += cur1 - buf1[(PP)]; buf1[(PP)] = cur1;                           \
      run2 += cur2 - buf2[(PP)]; buf2[(PP)] = cur2;                           \
      run3 += cur3 - buf3[(PP)]; buf3[(PP)] = cur3;                           \
      run4 += cur4 - buf4[(PP)]; buf4[(PP)] = cur4;                           \
      if (s >= 8) {                                                           \
        const float tavg = run0 * inv_kvol;                                   \
        const float pavg = run1 * inv_kvol;                                   \
        const float cross = run4 - pavg * run0;                               \
        const float tvar  = run2 - tavg * run0;                               \
        const float pvar  = run3 - pavg * run1;                               \
        acc += (cross * cross) / (tvar * pvar + 1e-5f);                       \
      }                                                                       \
    }                                                                         \
  } while (0)

  // ---- prologue: issue loads for slice 0 ----
  PRELOAD(0);

  for (int s0 = 0; s0 < NSTEP; s0 += 9) {
    ZBODY(0); ZBODY(1); ZBODY(2); ZBODY(3); ZBODY(4);
    ZBODY(5); ZBODY(6); ZBODY(7); ZBODY(8);
  }
#undef ZBODY
#undef PRELOAD

  // ---- reduction: wave shuffle -> LDS -> one atomicAdd per block ----
  #pragma unroll
  for (int off = 32; off > 0; off >>= 1)
    acc += __shfl_down(acc, off, 64);
  if ((tid & 63) == 0) wsum[tid >> 6] = acc;
  __syncthreads();
  if (tid == 0) {
    float tot = wsum[0] + wsum[1] + wsum[2] + wsum[3];
    atomicAdd(ws, tot);
  }
}

__global__ void ncc_finalize(const float* __restrict__ ws, float* __restrict__ out) {
  out[0] = -ws[0] * (1.0f / 8192000.0f);
}

extern "C" void kernel_launch(void* const* d_in, const int* in_sizes, int n_in,
                              void* d_out, int out_size, void* d_ws, size_t ws_size,
                              hipStream_t stream) {
  const float* pred   = (const float*)d_in[0];
  const float* target = (const float*)d_in[1];
  float* out = (float*)d_out;
  float* ws  = (float*)d_ws;

  ncc_zero_ws<<<1, 1, 0, stream>>>(ws);
  // grid: 10 x-tiles * 10 y-tiles * 8 z-chunks * 2 batches = 1600 blocks
  ncc_fused<<<1600, 256, 0, stream>>>(pred, target, ws);
  ncc_finalize<<<1, 1, 0, stream>>>(ws, out);
}